// Round 14
// baseline (118.473 us; speedup 1.0000x reference)
//
#include <hip/hip_runtime.h>
#include <math.h>
#include <stdint.h>

#define BATCH 64
#define SEQ   101
#define HID   512
#define NKQ   100      // N*K
#define KCLS  10
#define INV_TEMP 0.04419417382415922f   // 1/sqrt(512)

typedef short bf16x8 __attribute__((ext_vector_type(8)));
typedef float f32x4  __attribute__((ext_vector_type(4)));
typedef uint32_t u32x4 __attribute__((ext_vector_type(4)));

// HW packed f32->bf16 RNE: dst.lo = bf16(a), dst.hi = bf16(b)
__device__ inline uint32_t cvt2(float a, float b) {
    uint32_t r;
    asm("v_cvt_pk_bf16_f32 %0, %1, %2" : "=v"(r) : "v"(a), "v"(b));
    return r;
}
// truncation split: x == hi + lo to ~2^-17 rel (q & P planes)
__device__ inline void split_bf16(float x, short& hi, short& lo) {
    uint32_t u = __builtin_bit_cast(uint32_t, x);
    hi = (short)(u >> 16);
    float hf = __builtin_bit_cast(float, u & 0xFFFF0000u);
    float l  = x - hf;
    lo = (short)(__builtin_bit_cast(uint32_t, l) >> 16);
}

// ---------------------------------------------------------------------------
// r11 baseline (110.6 us validated) with phase 3 rebuilt as a WAVE-PRIVATE
// reg-staged LDS pipeline (T14) -- pure vanilla HIP, no global_load_lds, no
// raw s_barrier (the r12/r13 container-killers are gone):
//   * wave wv owns h-strip [16wv,16wv+16); it stages V[32j x 16h] fp32
//     panels for its own strip only -> ZERO barriers in phase 3.
//   * pipeline: chunk s+2 global loads -> ping-pong regs (iter s),
//     ds_write_b128 -> 2-slot LDS ring (iter s+1), ds_read+MFMA (iter s+2).
//     ~2 iterations of load-latency hiding, x16 waves/CU.
//   * V loads are 16B coalesced segments (vs r11's 1024 scalar gathers).
// Phases 1-2 byte-identical to r11. Numerics identical (absmax 0.015625).
// LDS: ring 32KB + q 33.3KB + sc 8.4KB = 74.5KB -> 2 blocks/CU.
// grid 448: b=id&63 (XCD affinity), i-tile=id>>6. 512 thr = 8 waves.
// ---------------------------------------------------------------------------
#define QST 520    // qhi/qlo row stride (shorts): 512 + 8 pad
#define SLOTSZ 16384
#define OFF_QHI 32768
#define OFF_QLO 49408
#define POOLSZ  66048

__global__ __launch_bounds__(512, 2)
void fused_attn(const float* __restrict__ q, const float* __restrict__ k,
                const float* __restrict__ v, const float* __restrict__ aw,
                float* __restrict__ out, float* __restrict__ attn) {
    __shared__ __align__(16) char pool[POOLSZ];
    __shared__ __align__(16) float sc[16][132];
    short (*qhi)[QST] = (short(*)[QST])(pool + OFF_QHI);
    short (*qlo)[QST] = (short(*)[QST])(pool + OFF_QLO);

    const int b   = blockIdx.x & 63;
    const int i0  = (blockIdx.x >> 6) * 16;
    const int tid = threadIdx.x;
    const int wv  = tid >> 6, lane = tid & 63;
    const int m   = lane & 15;
    const int g   = lane >> 4;
    const int kq  = g * 8;
    const int rq  = g * 4;
    const int j0w = wv * 16;

    const float* qb = q + (size_t)b * SEQ * HID;
    const float* kb = k + (size_t)b * SEQ * HID;
    const float* vb = v + (size_t)b * SEQ * HID;

    // ---------------- stage q hi/lo (once) ---------------------------------
    #pragma unroll
    for (int s = 0; s < 4; ++s) {
        const int f = tid + s * 512;
        const int r = f >> 7, c = (f & 127) << 2;
        const int gi = i0 + r;
        f32x4 x = {};
        if (gi < SEQ) x = *(const f32x4*)(qb + (size_t)gi * HID + c);
        short4 hv, lv;
        split_bf16(x[0], hv.x, lv.x);
        split_bf16(x[1], hv.y, lv.y);
        split_bf16(x[2], hv.z, lv.z);
        split_bf16(x[3], hv.w, lv.w);
        *(short4*)&qhi[r][c] = hv;
        *(short4*)&qlo[r][c] = lv;
    }
    __syncthreads();

    // ---------------- phase 1: QK^T, k direct from global (r11 form) -------
    f32x4 acc = {};
    {
        const int jg = j0w + m;
        const int jr = (jg > NKQ) ? NKQ : jg;   // clamp; junk cols zeroed later
        const float* kr = kb + (size_t)jr * HID + kq;
        f32x4 k0 = *(const f32x4*)(kr);
        f32x4 k1 = *(const f32x4*)(kr + 4);
        #pragma unroll
        for (int ks = 0; ks < 16; ++ks) {
            f32x4 n0 = {}, n1 = {};
            if (ks < 15) {
                n0 = *(const f32x4*)(kr + (ks + 1) * 32);
                n1 = *(const f32x4*)(kr + (ks + 1) * 32 + 4);
            }
            u32x4 kp;
            kp[0] = cvt2(k0[0], k0[1]); kp[1] = cvt2(k0[2], k0[3]);
            kp[2] = cvt2(k1[0], k1[1]); kp[3] = cvt2(k1[2], k1[3]);
            const bf16x8 kH = __builtin_bit_cast(bf16x8, kp);
            const bf16x8 qH = *(const bf16x8*)&qhi[m][ks * 32 + kq];
            const bf16x8 qL = *(const bf16x8*)&qlo[m][ks * 32 + kq];
            acc = __builtin_amdgcn_mfma_f32_16x16x32_bf16(qH, kH, acc, 0, 0, 0);
            acc = __builtin_amdgcn_mfma_f32_16x16x32_bf16(qL, kH, acc, 0, 0, 0);
            k0 = n0; k1 = n1;
        }
    }
    #pragma unroll
    for (int r = 0; r < 4; ++r)
        sc[rq + r][j0w + m] = acc[r];
    __syncthreads();

    // ---- V staging geometry (wave-private panel: 32 j x 16 h fp32) ---------
    // lane covers f = si*64+lane in [0,128): panel row j = f>>2, col4 = f&3.
    const int fj0 = lane >> 2,        fc0 = lane & 3;          // si = 0
    const int fj1 = (64 + lane) >> 2, fc1 = (64 + lane) & 3;   // si = 1
    float* vp0 = (float*)(pool + 0 * SLOTSZ) + wv * 512;       // slot 0 panel
    float* vp1 = (float*)(pool + 1 * SLOTSZ) + wv * 512;       // slot 1 panel
    f32x4 pfA[2], pfB[2];   // ping-pong regs: pfA = even chunks, pfB = odd

    // load chunk 0 and 1 into regs -- they fly under the softmax below
    {   // chunk 0: hc=0, jc=0
        const int r0 = (fj0 > NKQ) ? NKQ : fj0;
        const int r1 = (fj1 > NKQ) ? NKQ : fj1;
        pfA[0] = *(const f32x4*)(vb + (size_t)r0 * HID + j0w + fc0 * 4);
        pfA[1] = *(const f32x4*)(vb + (size_t)r1 * HID + j0w + fc1 * 4);
    }
    {   // chunk 1: hc=0, jc=1
        const int j0 = 32;
        const int r0 = (j0 + fj0 > NKQ) ? NKQ : j0 + fj0;
        const int r1 = (j0 + fj1 > NKQ) ? NKQ : j0 + fj1;
        pfB[0] = *(const f32x4*)(vb + (size_t)r0 * HID + j0w + fc0 * 4);
        pfB[1] = *(const f32x4*)(vb + (size_t)r1 * HID + j0w + fc1 * 4);
    }

    // ---------------- phase 2: softmax; normalized P stays in sc -----------
    {
        const int row = tid >> 5, t32 = tid & 31;
        const int gi  = i0 + row;
        float mx = -1e30f;
        for (int j = t32; j < SEQ; j += 32) {
            float s = sc[row][j] * INV_TEMP;
            sc[row][j] = s;
            mx = fmaxf(mx, s);
        }
        #pragma unroll
        for (int off = 1; off < 32; off <<= 1) mx = fmaxf(mx, __shfl_xor(mx, off));
        float sum = 0.f;
        for (int j = t32; j < SEQ; j += 32) {
            float e = __expf(sc[row][j] - mx);
            sc[row][j] = e;
            sum += e;
        }
        #pragma unroll
        for (int off = 1; off < 32; off <<= 1) sum += __shfl_xor(sum, off);
        const float inv = 1.f / sum;
        float* arow = attn + ((size_t)b * SEQ + gi) * SEQ;
        for (int j = t32; j < SEQ; j += 32) {
            float a = sc[row][j] * inv;
            sc[row][j] = a;                 // PV reads P from LDS
            if (gi < SEQ) arow[j] = a;      // tuple output
        }
        for (int j = SEQ + t32; j < 128; j += 32) sc[row][j] = 0.f;  // pad cols
    }
    __syncthreads();

    // ---------------- A fragments + class mask (hoisted) --------------------
    int ai = i0 + m; if (ai > NKQ) ai = NKQ;
    const int ci = ai / KCLS;
    uint32_t mbits = 0;
    #pragma unroll
    for (int ks = 0; ks < 4; ++ks)
        #pragma unroll
        for (int e = 0; e < 8; ++e)
            if (((ks * 32 + kq + e) / KCLS) == ci) mbits |= (1u << (ks * 8 + e));
    bf16x8 Ah[4], Al[4];
    #pragma unroll
    for (int ks = 0; ks < 4; ++ks) {
        const f32x4 u0 = *(const f32x4*)&sc[m][ks * 32 + kq];
        const f32x4 u1 = *(const f32x4*)&sc[m][ks * 32 + kq + 4];
        const float x[8] = {u0[0], u0[1], u0[2], u0[3], u1[0], u1[1], u1[2], u1[3]};
        #pragma unroll
        for (int e = 0; e < 8; ++e) {
            short h, l; split_bf16(x[e], h, l);
            Ah[ks][e] = h; Al[ks][e] = l;
        }
    }

    // write chunk 0 into slot 0 (compiler waits pfA's loads here)
    *(f32x4*)(vp0 + lane * 4)        = pfA[0];
    *(f32x4*)(vp0 + (64 + lane) * 4) = pfA[1];

    // ---------------- phase 3: wave-private pipelined PV, no barriers -------
    const int hl = j0w + m;                    // h column this lane owns
    f32x4 T = {}, U = {};
    float w0, w1, w2, w3, w4, w5, vNv, vi_r[4];
    #pragma unroll
    for (int s = 0; s < 16; ++s) {             // fully unrolled: all static
        const int jc = s & 3, hc = s >> 2;
        float* vpw = (s & 1) ? vp1 : vp0;      // slot being READ this iter
        float* vpn = (s & 1) ? vp0 : vp1;      // slot to WRITE (chunk s+1)

        // 1. land chunk s+1 (regs -> other slot); its reads finished at s-1
        if (s + 1 < 16) {
            const f32x4* pf = ((s + 1) & 1) ? pfB : pfA;
            *(f32x4*)(vpn + lane * 4)        = pf[0];
            *(f32x4*)(vpn + (64 + lane) * 4) = pf[1];
        }
        // 2. issue chunk s+2 global loads into the buffer just drained
        if (s + 2 < 16) {
            const int nc = s + 2, njc = nc & 3, nhc = nc >> 2;
            const int j0 = njc * 32, cb = nhc * 128 + j0w;
            const int r0 = (j0 + fj0 > NKQ) ? NKQ : j0 + fj0;
            const int r1 = (j0 + fj1 > NKQ) ? NKQ : j0 + fj1;
            f32x4* pf = ((s + 2) & 1) ? pfB : pfA;
            pf[0] = *(const f32x4*)(vb + (size_t)r0 * HID + cb + fc0 * 4);
            pf[1] = *(const f32x4*)(vb + (size_t)r1 * HID + cb + fc1 * 4);
        }
        // 3. hc start: reset acc, hoist epilogue scalars (adds MLP)
        if (jc == 0) {
            T = (f32x4){}; U = (f32x4){};
            const int h = (hc << 7) + hl;
            w0 = aw[0 * HID + h]; w1 = aw[1 * HID + h]; w2 = aw[2 * HID + h];
            w3 = aw[3 * HID + h]; w4 = aw[4 * HID + h]; w5 = aw[5 * HID + h];
            vNv = vb[(size_t)NKQ * HID + h];
            #pragma unroll
            for (int r = 0; r < 4; ++r) {
                const int i = i0 + rq + r;
                vi_r[r] = (i < NKQ) ? vb[(size_t)i * HID + h] : 0.f;
            }
        }
        // 4. consume panel: row g*8+e, col m (LDS in-order per wave)
        float xv[8];
        #pragma unroll
        for (int e = 0; e < 8; ++e)
            xv[e] = vpw[(kq + e) * 16 + m];
        u32x4 ph, pl;
        #pragma unroll
        for (int p = 0; p < 4; ++p) {
            const uint32_t h01 = cvt2(xv[2 * p], xv[2 * p + 1]);
            const float r0 = xv[2 * p]     - __builtin_bit_cast(float, h01 << 16);
            const float r1 = xv[2 * p + 1] - __builtin_bit_cast(float, h01 & 0xFFFF0000u);
            ph[p] = h01;
            pl[p] = cvt2(r0, r1);
        }
        const bf16x8 Bh = __builtin_bit_cast(bf16x8, ph);
        const bf16x8 Bl = __builtin_bit_cast(bf16x8, pl);
        bf16x8 Mh;
        #pragma unroll
        for (int e = 0; e < 8; ++e)
            Mh[e] = (mbits & (1u << (jc * 8 + e))) ? Ah[jc][e] : (short)0;
        T = __builtin_amdgcn_mfma_f32_16x16x32_bf16(Ah[jc], Bh, T, 0, 0, 0);
        T = __builtin_amdgcn_mfma_f32_16x16x32_bf16(Ah[jc], Bl, T, 0, 0, 0);
        T = __builtin_amdgcn_mfma_f32_16x16x32_bf16(Al[jc], Bh, T, 0, 0, 0);
        U = __builtin_amdgcn_mfma_f32_16x16x32_bf16(Mh,     Bh, U, 0, 0, 0);

        // 5. hc end: epilogue
        if (jc == 3) {
            const int h = (hc << 7) + hl;
            #pragma unroll
            for (int r = 0; r < 4; ++r) {
                const int i = i0 + rq + r;
                if (i >= SEQ) continue;
                const int il = rq + r;
                const float t = T[r], u = U[r];
                const float aiN = sc[il][NKQ];
                float o;
                if (i < NKQ) {
                    const float aii = sc[il][i];
                    o = w2 * t + (w1 - w2) * u + (w0 - w1) * aii * vi_r[r]
                      + (w3 - w2) * aiN * vNv;
                } else {
                    o = w4 * t + (w5 - w4) * aiN * vNv;
                }
                out[((size_t)b * SEQ + i) * HID + h] = o;
            }
        }
    }
}

extern "C" void kernel_launch(void* const* d_in, const int* in_sizes, int n_in,
                              void* d_out, int out_size, void* d_ws, size_t ws_size,
                              hipStream_t stream) {
    const float* q  = (const float*)d_in[0];
    const float* k  = (const float*)d_in[1];
    const float* v  = (const float*)d_in[2];
    const float* aw = (const float*)d_in[3];
    float* out  = (float*)d_out;
    float* attn = out + (size_t)BATCH * SEQ * HID;   // tuple output: [out | attn]
    (void)d_ws; (void)ws_size;

    fused_attn<<<dim3(448), dim3(512), 0, stream>>>(q, k, v, aw, out, attn);
}